// Round 9
// baseline (182.456 us; speedup 1.0000x reference)
//
#include <hip/hip_runtime.h>

#define NN 4096
#define DD 2048
#define MARGIN_F 0.3f
#define NT64 (NN / 64)   // 64 row-blocks
#define NTILES 2080      // 64*65/2 upper-triangular 64x64 wave-tiles
#define NBLK 520         // NTILES / 4 waves per block
#define QS (127.0f / 6.0f)
#define C2 (2.0f * (6.0f / 127.0f) * (6.0f / 127.0f))  // 2/QS^2

typedef __attribute__((ext_vector_type(4))) int i32x4;

__device__ __forceinline__ unsigned q8(float v) {
    int i = __float2int_rn(v * QS);
    i = min(127, max(-127, i));
    return (unsigned)(i & 255);
}

// 1024 blocks x 4 waves; each wave quantizes one row (int8) + fp32
// sum-of-squares; init ap/an/counter.
__global__ __launch_bounds__(256) void prep_kernel(const float* __restrict__ x,
                                                   unsigned char* __restrict__ xq,
                                                   float* __restrict__ sq,
                                                   unsigned int* __restrict__ ap,
                                                   unsigned int* __restrict__ an,
                                                   int* __restrict__ counter) {
    const int wave = threadIdx.x >> 6, lane = threadIdx.x & 63;
    const int row = blockIdx.x * 4 + wave;
    const float* xr = x + (size_t)row * DD;
    unsigned int* orow = (unsigned int*)(xq + (size_t)row * DD);
    float s = 0.0f;
#pragma unroll
    for (int j = 0; j < 8; ++j) {
        float4 v = ((const float4*)xr)[j * 64 + lane];
        s += v.x * v.x + v.y * v.y + v.z * v.z + v.w * v.w;
        orow[j * 64 + lane] = q8(v.x) | (q8(v.y) << 8) | (q8(v.z) << 16) | (q8(v.w) << 24);
    }
    for (int off = 32; off > 0; off >>= 1) s += __shfl_down(s, off, 64);
    if (lane == 0) {
        sq[row] = s;
        ap[row] = 0u;            // hardest-positive max starts at 0
        an[row] = 0x7F800000u;   // +inf
    }
    if (threadIdx.x == 0 && blockIdx.x == 0) counter[0] = 0;
}

// LDS-FREE symmetric batch-hard GEMM (int8, exact int32 dots): one 64x64
// wave-tile per wave, 2080 upper-triangular tiles, 520 blocks x 4 waves.
// Fragments for mfma_i32_16x16x64_i8 are loaded DIRECTLY global->VGPR:
// lane (c=lane&15, q=lane>>4) needs bytes row*2048 + q*16 + k — one
// dwordx4 with saddr + 32-bit voffset + compile-time imm k (full unroll).
// Register double-buffer: load K-step it+1 while 16 MFMAs run on step it.
// NO barriers / NO vmcnt(0) drains in the K-loop — the structural stall of
// the R1-R8 LDS pipeline (m97 plateau) is gone; compiler emits fine-grained
// vmcnt(N) since VGPR buffers cannot alias. X-int8 (8 MB) is L2/L3
// resident. Both-side epilogues (idempotent max/min, gi!=gj guards the
// diagonal); fused last-block finalize.
__global__ __launch_bounds__(256, 2) void gemm_reduce_kernel(
    const unsigned char* __restrict__ xq,
    const float* __restrict__ sq,
    const int* __restrict__ labels,
    unsigned int* __restrict__ ap,
    unsigned int* __restrict__ an,
    int* __restrict__ counter,
    float* __restrict__ out) {
    __shared__ int flag;
    __shared__ float ssum[4];
    __shared__ int scnt[4];

    const int t = threadIdx.x;
    const int lane = t & 63;
    const int wave = t >> 6;
    const int c = lane & 15;   // fragment row/col lane
    const int q = lane >> 4;   // k-quad

    // decode this wave's upper-triangular 64x64 tile (bi <= bj)
    int rem = blockIdx.x * 4 + wave;
    int bi = 0;
    while (rem >= NT64 - bi) { rem -= NT64 - bi; ++bi; }
    const int bj = bi + rem;
    const int row0 = bi * 64;
    const int col0 = bj * 64;

    // 32-bit byte offsets (saddr-form loads: SGPR base + voffset + imm k)
    unsigned offA[4], offB[4];
#pragma unroll
    for (int mi = 0; mi < 4; ++mi)
        offA[mi] = (unsigned)(row0 + mi * 16 + c) * DD + q * 16;
#pragma unroll
    for (int ni = 0; ni < 4; ++ni)
        offB[ni] = (unsigned)(col0 + ni * 16 + c) * DD + q * 16;

    i32x4 acc[4][4];
#pragma unroll
    for (int mi = 0; mi < 4; ++mi)
#pragma unroll
        for (int ni = 0; ni < 4; ++ni)
            acc[mi][ni] = (i32x4){0, 0, 0, 0};

    i32x4 a0[4], b0[4], a1[4], b1[4];
#pragma unroll
    for (int mi = 0; mi < 4; ++mi) a0[mi] = *(const i32x4*)(xq + offA[mi]);
#pragma unroll
    for (int ni = 0; ni < 4; ++ni) b0[ni] = *(const i32x4*)(xq + offB[ni]);

    // 32 K-steps of 64 bytes, 2x unrolled with register ping-pong.
#pragma unroll
    for (int it = 0; it < 16; ++it) {
        const int k1 = (2 * it + 1) * 64;
#pragma unroll
        for (int mi = 0; mi < 4; ++mi) a1[mi] = *(const i32x4*)(xq + offA[mi] + k1);
#pragma unroll
        for (int ni = 0; ni < 4; ++ni) b1[ni] = *(const i32x4*)(xq + offB[ni] + k1);
#pragma unroll
        for (int mi = 0; mi < 4; ++mi)
#pragma unroll
            for (int ni = 0; ni < 4; ++ni)
                acc[mi][ni] = __builtin_amdgcn_mfma_i32_16x16x64_i8(
                    a0[mi], b0[ni], acc[mi][ni], 0, 0, 0);
        if (it < 15) {
            const int k2 = (2 * it + 2) * 64;
#pragma unroll
            for (int mi = 0; mi < 4; ++mi) a0[mi] = *(const i32x4*)(xq + offA[mi] + k2);
#pragma unroll
            for (int ni = 0; ni < 4; ++ni) b0[ni] = *(const i32x4*)(xq + offB[ni] + k2);
        }
#pragma unroll
        for (int mi = 0; mi < 4; ++mi)
#pragma unroll
            for (int ni = 0; ni < 4; ++ni)
                acc[mi][ni] = __builtin_amdgcn_mfma_i32_16x16x64_i8(
                    a1[mi], b1[ni], acc[mi][ni], 0, 0, 0);
    }

    // --- Epilogue ---
    // C/D layout 16x16: col = lane&15 (c), row = q*4 + reg [m89/m91;
    // dtype-independent m121-m128]
    float sq_col[4];
    int lab_col[4];
#pragma unroll
    for (int ni = 0; ni < 4; ++ni) {
        const int gj = col0 + ni * 16 + c;
        sq_col[ni] = sq[gj];
        lab_col[ni] = labels[gj];
    }
    int lab_row[4][4];
    float dist[4][4][4];
#pragma unroll
    for (int mi = 0; mi < 4; ++mi) {
#pragma unroll
        for (int r = 0; r < 4; ++r) {
            const int gi = row0 + mi * 16 + q * 4 + r;
            const float sqi = sq[gi];
            lab_row[mi][r] = labels[gi];
#pragma unroll
            for (int ni = 0; ni < 4; ++ni) {
                float d2 = sqi + sq_col[ni] - C2 * (float)acc[mi][ni][r];
                dist[mi][ni][r] = sqrtf(fmaxf(d2, 0.0f));
            }
        }
    }

    // Row-side: rows gi vs this tile's 64 columns.
#pragma unroll
    for (int mi = 0; mi < 4; ++mi) {
#pragma unroll
        for (int r = 0; r < 4; ++r) {
            const int gi = row0 + mi * 16 + q * 4 + r;
            const int li = lab_row[mi][r];
            float apm = 0.0f;
            float anm = __builtin_inff();
#pragma unroll
            for (int ni = 0; ni < 4; ++ni) {
                const int gj = col0 + ni * 16 + c;
                const float d = dist[mi][ni][r];
                if (li == lab_col[ni]) {
                    if (gi != gj) apm = fmaxf(apm, d);  // exclude diagonal
                } else {
                    anm = fminf(anm, d);
                }
            }
#pragma unroll
            for (int off = 1; off < 16; off <<= 1) {
                apm = fmaxf(apm, __shfl_xor(apm, off, 16));
                anm = fminf(anm, __shfl_xor(anm, off, 16));
            }
            if (c == 0) {
                atomicMax(&ap[gi], __float_as_uint(apm));
                atomicMin(&an[gi], __float_as_uint(anm));
            }
        }
    }

    // Column-side (transposed): S(gi,gj) also serves row gj (dupes
    // idempotent; diagonal guarded).
#pragma unroll
    for (int ni = 0; ni < 4; ++ni) {
        const int gj = col0 + ni * 16 + c;
        const int lj = lab_col[ni];
        float apm = 0.0f;
        float anm = __builtin_inff();
#pragma unroll
        for (int mi = 0; mi < 4; ++mi) {
#pragma unroll
            for (int r = 0; r < 4; ++r) {
                const int gi = row0 + mi * 16 + q * 4 + r;
                const float d = dist[mi][ni][r];
                if (lj == lab_row[mi][r]) {
                    if (gi != gj) apm = fmaxf(apm, d);  // exclude diagonal
                } else {
                    anm = fminf(anm, d);
                }
            }
        }
        apm = fmaxf(apm, __shfl_xor(apm, 16, 64));
        anm = fminf(anm, __shfl_xor(anm, 16, 64));
        apm = fmaxf(apm, __shfl_xor(apm, 32, 64));
        anm = fminf(anm, __shfl_xor(anm, 32, 64));
        if (q == 0) {
            atomicMax(&ap[gj], __float_as_uint(apm));
            atomicMin(&an[gj], __float_as_uint(anm));
        }
    }

    // --- Fused finalize: last block to finish reduces the loss ---
    __syncthreads();  // drains this block's atomics (vmcnt) before release
    if (t == 0) {
        int old = __hip_atomic_fetch_add(counter, 1, __ATOMIC_ACQ_REL,
                                         __HIP_MEMORY_SCOPE_AGENT);
        flag = (old == NBLK - 1) ? 1 : 0;
    }
    __syncthreads();
    if (flag) {
        float sum = 0.0f;
        int cnt = 0;
        for (int i = t; i < NN; i += 256) {
            const float a = __uint_as_float(__hip_atomic_load(
                &ap[i], __ATOMIC_RELAXED, __HIP_MEMORY_SCOPE_AGENT));
            const float b = __uint_as_float(__hip_atomic_load(
                &an[i], __ATOMIC_RELAXED, __HIP_MEMORY_SCOPE_AGENT));
            if ((a > 0.0f) && (b < __builtin_inff())) {
                sum += fmaxf(a - b + MARGIN_F, 0.0f);
                cnt += 1;
            }
        }
        for (int off = 32; off > 0; off >>= 1) {
            sum += __shfl_down(sum, off, 64);
            cnt += __shfl_down(cnt, off, 64);
        }
        if (lane == 0) { ssum[wave] = sum; scnt[wave] = cnt; }
        __syncthreads();
        if (t == 0) {
            float s = 0.0f; int n = 0;
#pragma unroll
            for (int w = 0; w < 4; ++w) { s += ssum[w]; n += scnt[w]; }
            out[0] = (n > 0) ? s / (float)n : 0.0f;
        }
    }
}

extern "C" void kernel_launch(void* const* d_in, const int* in_sizes, int n_in,
                              void* d_out, int out_size, void* d_ws, size_t ws_size,
                              hipStream_t stream) {
    const float* x = (const float*)d_in[0];
    const int* labels = (const int*)d_in[1];
    float* out = (float*)d_out;

    char* ws = (char*)d_ws;
    unsigned char* xq = (unsigned char*)ws;                         // 4096*2048 B
    float* sq = (float*)(ws + (size_t)NN * DD);
    unsigned int* ap = (unsigned int*)(ws + (size_t)NN * DD + (size_t)NN * 4);
    unsigned int* an = (unsigned int*)(ws + (size_t)NN * DD + (size_t)NN * 8);
    int* counter = (int*)(ws + (size_t)NN * DD + (size_t)NN * 12);

    prep_kernel<<<NN / 4, 256, 0, stream>>>(x, xq, sq, ap, an, counter);
    gemm_reduce_kernel<<<NBLK, 256, 0, stream>>>(xq, sq, labels, ap, an, counter, out);
}

// Round 10
// 153.401 us; speedup vs baseline: 1.1894x; 1.1894x over previous
//
#include <hip/hip_runtime.h>

#define NN 4096
#define DD 2048
#define MARGIN_F 0.3f
#define NPAIRS 528      // 32*33/2 upper-triangular 128x128 tiles
#define BK 128          // K bytes per stage
#define NSTAGE (DD / BK)  // 16
#define QS (127.0f / 6.0f)
#define C2 (2.0f * (6.0f / 127.0f) * (6.0f / 127.0f))  // 2/QS^2

typedef __attribute__((ext_vector_type(4))) int i32x4;

__device__ __forceinline__ unsigned q8(float v) {
    int i = __float2int_rn(v * QS);
    i = min(127, max(-127, i));
    return (unsigned)(i & 255);
}

// 1024 blocks x 4 waves; each wave quantizes one row (int8) + fp32
// sum-of-squares; init ap/an/counter.
__global__ __launch_bounds__(256) void prep_kernel(const float* __restrict__ x,
                                                   unsigned char* __restrict__ xq,
                                                   float* __restrict__ sq,
                                                   unsigned int* __restrict__ ap,
                                                   unsigned int* __restrict__ an,
                                                   int* __restrict__ counter) {
    const int wave = threadIdx.x >> 6, lane = threadIdx.x & 63;
    const int row = blockIdx.x * 4 + wave;
    const float* xr = x + (size_t)row * DD;
    unsigned int* orow = (unsigned int*)(xq + (size_t)row * DD);
    float s = 0.0f;
#pragma unroll
    for (int j = 0; j < 8; ++j) {
        float4 v = ((const float4*)xr)[j * 64 + lane];
        s += v.x * v.x + v.y * v.y + v.z * v.z + v.w * v.w;
        orow[j * 64 + lane] = q8(v.x) | (q8(v.y) << 8) | (q8(v.z) << 16) | (q8(v.w) << 24);
    }
    for (int off = 32; off > 0; off >>= 1) s += __shfl_down(s, off, 64);
    if (lane == 0) {
        sq[row] = s;
        ap[row] = 0u;            // hardest-positive max starts at 0
        an[row] = 0x7F800000u;   // +inf
    }
    if (threadIdx.x == 0 && blockIdx.x == 0) counter[0] = 0;
}

// PRODUCER-CONSUMER symmetric batch-hard GEMM (int8): the barrier-free
// K-loop. 528 triangular 128x128 tiles, 320 threads = 1 producer wave +
// 4 consumer waves (2x2 of 64x64, 4x4 frags of mfma_i32_16x16x64_i8).
// Ring of 2 LDS slots (32 KB each). The producer is the ONLY wave that
// waits vmcnt (s_waitcnt 0x0F70 = vmcnt(0), lgkm/exp don't-care) — it
// issues 32 global_load_lds per stage, drains, then releases a monotonic
// ready-flag. Consumers spin on ready (LDS acquire), ds_read + MFMA,
// bump a monotonic done-counter (release drains their ds_reads). No
// __syncthreads, no whole-block vmcnt(0) drain in the K-loop — the
// structural stall of R1-R8 (m97 plateau). R7's XOR swizzle (0 conflicts)
// and fragment mapping are kept verbatim. Both-side epilogues (idempotent
// max/min, gi!=gj guards diagonal); fused last-block finalize.
__global__ __launch_bounds__(320, 3) void gemm_reduce_kernel(
    const unsigned char* __restrict__ xq,
    const float* __restrict__ sq,
    const int* __restrict__ labels,
    unsigned int* __restrict__ ap,
    unsigned int* __restrict__ an,
    int* __restrict__ counter,
    float* __restrict__ out) {
    __shared__ __align__(16) unsigned char tiles[2][2][16384];  // [slot][A/B] 64 KB
    __shared__ int ready[2];   // monotonic: stage s published => ready[s&1] = s+1
    __shared__ int done[2];    // monotonic: 4 increments per completed stage
    __shared__ int flag;
    __shared__ float ssum[5];
    __shared__ int scnt[5];

    const int t = threadIdx.x;
    const int lane = t & 63;
    const int wave = t >> 6;

    // decode upper-triangular tile (bi <= bj)
    int rem = blockIdx.x;
    int bi = 0;
    while (rem >= 32 - bi) { rem -= 32 - bi; ++bi; }
    const int bj = bi + rem;
    const int row0 = bi * 128;
    const int col0 = bj * 128;

    if (t == 0) { ready[0] = ready[1] = 0; done[0] = done[1] = 0; }
    __syncthreads();

    if (wave == 4) {
        // ---------------- producer ----------------
        // chunk ca = i*64 + lane: row = ca>>3, col = ca&7, src col XOR-swizzled
        unsigned offA[16], offB[16];
#pragma unroll
        for (int i = 0; i < 16; ++i) {
            const int ca = i * 64 + lane;
            const int row = ca >> 3;
            const int sc = (ca & 7) ^ (row & 7);
            offA[i] = (unsigned)(row0 + row) * DD + sc * 16;
            offB[i] = (unsigned)(col0 + row) * DD + sc * 16;
        }
        for (int s = 0; s < NSTAGE; ++s) {
            const int slot = s & 1;
            if (s >= 2) {  // wait until stage s-2 fully consumed (4*(s>>1) total)
                while (__hip_atomic_load(&done[slot], __ATOMIC_ACQUIRE,
                                         __HIP_MEMORY_SCOPE_WORKGROUP) < 4 * (s >> 1))
                    __builtin_amdgcn_s_sleep(1);
            }
            const unsigned k0 = (unsigned)s * BK;
#pragma unroll
            for (int i = 0; i < 16; ++i)
                __builtin_amdgcn_global_load_lds(
                    (const __attribute__((address_space(1))) void*)(xq + offA[i] + k0),
                    (__attribute__((address_space(3))) void*)&tiles[slot][0][(i * 64 + lane) * 16],
                    16, 0, 0);
#pragma unroll
            for (int i = 0; i < 16; ++i)
                __builtin_amdgcn_global_load_lds(
                    (const __attribute__((address_space(1))) void*)(xq + offB[i] + k0),
                    (__attribute__((address_space(3))) void*)&tiles[slot][1][(i * 64 + lane) * 16],
                    16, 0, 0);
            __builtin_amdgcn_s_waitcnt(0x0F70);  // vmcnt(0) only (this wave's loads)
            __hip_atomic_store(&ready[slot], s + 1, __ATOMIC_RELEASE,
                               __HIP_MEMORY_SCOPE_WORKGROUP);
        }
    } else {
        // ---------------- consumers ----------------
        const int c = lane & 15;          // fragment column lane
        const int q = lane >> 4;          // quad id
        const int wr = (wave >> 1) * 64;  // wave row offset
        const int wc = (wave & 1) * 64;   // wave col offset

        i32x4 acc[4][4];
#pragma unroll
        for (int mi = 0; mi < 4; ++mi)
#pragma unroll
            for (int ni = 0; ni < 4; ++ni)
                acc[mi][ni] = (i32x4){0, 0, 0, 0};

        for (int s = 0; s < NSTAGE; ++s) {
            const int slot = s & 1;
            while (__hip_atomic_load(&ready[slot], __ATOMIC_ACQUIRE,
                                     __HIP_MEMORY_SCOPE_WORKGROUP) < s + 1)
                __builtin_amdgcn_s_sleep(1);
            const i32x4* Av = (const i32x4*)tiles[slot][0];
            const i32x4* Bv = (const i32x4*)tiles[slot][1];
#pragma unroll
            for (int ks = 0; ks < 2; ++ks) {
                i32x4 af[4], bf[4];
#pragma unroll
                for (int mi = 0; mi < 4; ++mi) {
                    const int r = wr + mi * 16 + c;
                    af[mi] = Av[r * 8 + ((q + 4 * ks) ^ (r & 7))];
                }
#pragma unroll
                for (int ni = 0; ni < 4; ++ni) {
                    const int r = wc + ni * 16 + c;
                    bf[ni] = Bv[r * 8 + ((q + 4 * ks) ^ (r & 7))];
                }
#pragma unroll
                for (int mi = 0; mi < 4; ++mi)
#pragma unroll
                    for (int ni = 0; ni < 4; ++ni)
                        acc[mi][ni] = __builtin_amdgcn_mfma_i32_16x16x64_i8(
                            af[mi], bf[ni], acc[mi][ni], 0, 0, 0);
            }
            // release: drains this wave's ds_reads before the increment lands
            __hip_atomic_fetch_add(&done[slot], 1, __ATOMIC_RELEASE,
                                   __HIP_MEMORY_SCOPE_WORKGROUP);
        }

        // --- Epilogue (consumer waves only) ---
        // C/D layout 16x16: col = lane&15 (c), row = q*4 + reg [m89/m91;
        // dtype-independent m121-m128]. dist stored in-place in acc.
        float sq_col[4];
        int lab_col[4];
#pragma unroll
        for (int ni = 0; ni < 4; ++ni) {
            const int gj = col0 + wc + ni * 16 + c;
            sq_col[ni] = sq[gj];
            lab_col[ni] = labels[gj];
        }
        int lab_row[4][4];
#pragma unroll
        for (int mi = 0; mi < 4; ++mi) {
#pragma unroll
            for (int r = 0; r < 4; ++r) {
                const int gi = row0 + wr + mi * 16 + q * 4 + r;
                const float sqi = sq[gi];
                lab_row[mi][r] = labels[gi];
#pragma unroll
                for (int ni = 0; ni < 4; ++ni) {
                    float d2 = sqi + sq_col[ni] - C2 * (float)acc[mi][ni][r];
                    acc[mi][ni][r] = __float_as_int(sqrtf(fmaxf(d2, 0.0f)));
                }
            }
        }

        // Row-side: rows gi vs this wave's 64 columns.
#pragma unroll
        for (int mi = 0; mi < 4; ++mi) {
#pragma unroll
            for (int r = 0; r < 4; ++r) {
                const int gi = row0 + wr + mi * 16 + q * 4 + r;
                const int li = lab_row[mi][r];
                float apm = 0.0f;
                float anm = __builtin_inff();
#pragma unroll
                for (int ni = 0; ni < 4; ++ni) {
                    const int gj = col0 + wc + ni * 16 + c;
                    const float d = __int_as_float(acc[mi][ni][r]);
                    if (li == lab_col[ni]) {
                        if (gi != gj) apm = fmaxf(apm, d);  // exclude diagonal
                    } else {
                        anm = fminf(anm, d);
                    }
                }
#pragma unroll
                for (int off = 1; off < 16; off <<= 1) {
                    apm = fmaxf(apm, __shfl_xor(apm, off, 16));
                    anm = fminf(anm, __shfl_xor(anm, off, 16));
                }
                if (c == 0) {
                    atomicMax(&ap[gi], __float_as_uint(apm));
                    atomicMin(&an[gi], __float_as_uint(anm));
                }
            }
        }

        // Column-side (transposed): S(gi,gj) also serves row gj.
#pragma unroll
        for (int ni = 0; ni < 4; ++ni) {
            const int gj = col0 + wc + ni * 16 + c;
            const int lj = lab_col[ni];
            float apm = 0.0f;
            float anm = __builtin_inff();
#pragma unroll
            for (int mi = 0; mi < 4; ++mi) {
#pragma unroll
                for (int r = 0; r < 4; ++r) {
                    const int gi = row0 + wr + mi * 16 + q * 4 + r;
                    const float d = __int_as_float(acc[mi][ni][r]);
                    if (lj == lab_row[mi][r]) {
                        if (gi != gj) apm = fmaxf(apm, d);  // exclude diagonal
                    } else {
                        anm = fminf(anm, d);
                    }
                }
            }
            apm = fmaxf(apm, __shfl_xor(apm, 16, 64));
            anm = fminf(anm, __shfl_xor(anm, 16, 64));
            apm = fmaxf(apm, __shfl_xor(apm, 32, 64));
            anm = fminf(anm, __shfl_xor(anm, 32, 64));
            if (q == 0) {
                atomicMax(&ap[gj], __float_as_uint(apm));
                atomicMin(&an[gj], __float_as_uint(anm));
            }
        }
    }

    // --- Fused finalize: last block to finish reduces the loss ---
    __syncthreads();  // all 5 waves; drains atomics before counter release
    if (t == 0) {
        int old = __hip_atomic_fetch_add(counter, 1, __ATOMIC_ACQ_REL,
                                         __HIP_MEMORY_SCOPE_AGENT);
        flag = (old == NPAIRS - 1) ? 1 : 0;
    }
    __syncthreads();
    if (flag) {
        float sum = 0.0f;
        int cnt = 0;
        for (int i = t; i < NN; i += 320) {
            const float a = __uint_as_float(__hip_atomic_load(
                &ap[i], __ATOMIC_RELAXED, __HIP_MEMORY_SCOPE_AGENT));
            const float b = __uint_as_float(__hip_atomic_load(
                &an[i], __ATOMIC_RELAXED, __HIP_MEMORY_SCOPE_AGENT));
            if ((a > 0.0f) && (b < __builtin_inff())) {
                sum += fmaxf(a - b + MARGIN_F, 0.0f);
                cnt += 1;
            }
        }
        for (int off = 32; off > 0; off >>= 1) {
            sum += __shfl_down(sum, off, 64);
            cnt += __shfl_down(cnt, off, 64);
        }
        if (lane == 0) { ssum[wave] = sum; scnt[wave] = cnt; }
        __syncthreads();
        if (t == 0) {
            float s = 0.0f; int n = 0;
#pragma unroll
            for (int w = 0; w < 5; ++w) { s += ssum[w]; n += scnt[w]; }
            out[0] = (n > 0) ? s / (float)n : 0.0f;
        }
    }
}

extern "C" void kernel_launch(void* const* d_in, const int* in_sizes, int n_in,
                              void* d_out, int out_size, void* d_ws, size_t ws_size,
                              hipStream_t stream) {
    const float* x = (const float*)d_in[0];
    const int* labels = (const int*)d_in[1];
    float* out = (float*)d_out;

    char* ws = (char*)d_ws;
    unsigned char* xq = (unsigned char*)ws;                         // 4096*2048 B
    float* sq = (float*)(ws + (size_t)NN * DD);
    unsigned int* ap = (unsigned int*)(ws + (size_t)NN * DD + (size_t)NN * 4);
    unsigned int* an = (unsigned int*)(ws + (size_t)NN * DD + (size_t)NN * 8);
    int* counter = (int*)(ws + (size_t)NN * DD + (size_t)NN * 12);

    prep_kernel<<<NN / 4, 256, 0, stream>>>(x, xq, sq, ap, an, counter);
    gemm_reduce_kernel<<<NPAIRS, 320, 0, stream>>>(xq, sq, labels, ap, an, counter, out);
}

// Round 11
// 141.487 us; speedup vs baseline: 1.2896x; 1.0842x over previous
//
#include <hip/hip_runtime.h>

#define NN 4096
#define DD 2048
#define MARGIN_F 0.3f
#define NTILES 1056  // 64x128 tiles covering the upper triangle (dupes OK)
#define BK 256       // K bytes per stage
#define NIT (DD / BK)  // 8
#define QS (127.0f / 6.0f)
#define C2 (2.0f * (6.0f / 127.0f) * (6.0f / 127.0f))  // 2/QS^2

typedef __attribute__((ext_vector_type(4))) int i32x4;

__device__ __forceinline__ unsigned q8(float v) {
    int i = __float2int_rn(v * QS);
    i = min(127, max(-127, i));
    return (unsigned)(i & 255);
}

// 1024 blocks x 4 waves; each wave quantizes one row (int8) + fp32
// sum-of-squares; init ap/an/counter.
__global__ __launch_bounds__(256) void prep_kernel(const float* __restrict__ x,
                                                   unsigned char* __restrict__ xq,
                                                   float* __restrict__ sq,
                                                   unsigned int* __restrict__ ap,
                                                   unsigned int* __restrict__ an,
                                                   int* __restrict__ counter) {
    const int wave = threadIdx.x >> 6, lane = threadIdx.x & 63;
    const int row = blockIdx.x * 4 + wave;
    const float* xr = x + (size_t)row * DD;
    unsigned int* orow = (unsigned int*)(xq + (size_t)row * DD);
    float s = 0.0f;
#pragma unroll
    for (int j = 0; j < 8; ++j) {
        float4 v = ((const float4*)xr)[j * 64 + lane];
        s += v.x * v.x + v.y * v.y + v.z * v.z + v.w * v.w;
        orow[j * 64 + lane] = q8(v.x) | (q8(v.y) << 8) | (q8(v.z) << 16) | (q8(v.w) << 24);
    }
    for (int off = 32; off > 0; off >>= 1) s += __shfl_down(s, off, 64);
    if (lane == 0) {
        sq[row] = s;
        ap[row] = 0u;            // hardest-positive max starts at 0
        an[row] = 0x7F800000u;   // +inf
    }
    if (threadIdx.x == 0 && blockIdx.x == 0) counter[0] = 0;
}

// Symmetric batch-hard GEMM, int8, R7 structure with BK=256 (NIT=8):
// ten rounds fit T ~ N_iter x (fixed ~7-10K cyc barrier-drain + content),
// so halve the sequential barrier-iterations at constant grid (1056 blocks,
// 64x128 tiles, ~4/CU). LDS 48 KB -> 3 blocks/CU. 16-chunk rows use
// col' = col ^ (row&15) swizzle (2-way bank aliasing only = free).
// mfma_i32_16x16x64_i8, wave = 64 rows x 32 cols (4x2 frags), 4 k-chunks
// per stage. Both-side epilogues (idempotent max/min, gi!=gj guards the
// diagonal); fused last-block finalize. K-phase stagger (int = exact).
__global__ __launch_bounds__(256) void gemm_reduce_kernel(
    const unsigned char* __restrict__ xq,
    const float* __restrict__ sq,
    const int* __restrict__ labels,
    unsigned int* __restrict__ ap,
    unsigned int* __restrict__ an,
    int* __restrict__ counter,
    float* __restrict__ out) {
    __shared__ __align__(16) unsigned char As[64 * BK];    // 16 KB
    __shared__ __align__(16) unsigned char Bs[128 * BK];   // 32 KB

    // decode tile: row-block mi64 (64 rows), col-block nj (128 cols),
    // tiles with 128*nj + 127 >= 64*mi64, i.e. nj >= floor(mi64/2).
    int rem = blockIdx.x;
    int mi64 = 0;
    while (rem >= 32 - (mi64 >> 1)) { rem -= 32 - (mi64 >> 1); ++mi64; }
    const int nj = (mi64 >> 1) + rem;
    const int row0 = mi64 * 64;
    const int col0 = nj * 128;
    const int phase = blockIdx.x & (NIT - 1);  // K-start stagger

    const int t = threadIdx.x;
    const int lane = t & 63;
    const int wave = t >> 6;
    const int c = lane & 15;   // fragment column lane
    const int q = lane >> 4;   // k-quad
    const int wc = wave * 32;  // wave col offset (rows shared by all waves)

    i32x4 acc[4][2];
#pragma unroll
    for (int mi = 0; mi < 4; ++mi)
#pragma unroll
        for (int ni = 0; ni < 2; ++ni)
            acc[mi][ni] = (i32x4){0, 0, 0, 0};

    // Staging: rows are 256 B = 16 chunks of 16 B. A tile 64 rows = 1024
    // chunks (4/thread), B tile 128 rows = 2048 chunks (8/thread).
    // Chunk ci = t + 256*s: row = ci>>4 = (t>>4) + 16*s, col = t&15;
    // source col XOR-swizzled: col ^ (row&15), and row&15 = (t>>4)&15 is
    // s-invariant, so one swizzled col per thread.
    const int rowb = t >> 4;
    const int colsw = (t & 15) ^ (rowb & 15);
    const unsigned char* gA[4];
    const unsigned char* gB[8];
#pragma unroll
    for (int s = 0; s < 4; ++s)
        gA[s] = xq + (size_t)(row0 + rowb + 16 * s) * DD + colsw * 16;
#pragma unroll
    for (int s = 0; s < 8; ++s)
        gB[s] = xq + (size_t)(col0 + rowb + 16 * s) * DD + colsw * 16;

    for (int it = 0; it < NIT; ++it) {
        const int k0 = ((it + phase) & (NIT - 1)) * BK;
#pragma unroll
        for (int s = 0; s < 4; ++s)
            __builtin_amdgcn_global_load_lds(
                (const __attribute__((address_space(1))) void*)(gA[s] + k0),
                (__attribute__((address_space(3))) void*)&As[(t + 256 * s) * 16],
                16, 0, 0);
#pragma unroll
        for (int s = 0; s < 8; ++s)
            __builtin_amdgcn_global_load_lds(
                (const __attribute__((address_space(1))) void*)(gB[s] + k0),
                (__attribute__((address_space(3))) void*)&Bs[(t + 256 * s) * 16],
                16, 0, 0);
        __syncthreads();

        const i32x4* Av = (const i32x4*)As;
        const i32x4* Bv = (const i32x4*)Bs;
#pragma unroll
        for (int ks = 0; ks < 4; ++ks) {
            const int kc = q + 4 * ks;  // k-chunk for this lane's fragment
            i32x4 af[4], bfr[2];
#pragma unroll
            for (int mi = 0; mi < 4; ++mi) {
                const int r = mi * 16 + c;
                af[mi] = Av[r * 16 + (kc ^ (r & 15))];
            }
#pragma unroll
            for (int ni = 0; ni < 2; ++ni) {
                const int r = wc + ni * 16 + c;
                bfr[ni] = Bv[r * 16 + (kc ^ (r & 15))];
            }
#pragma unroll
            for (int mi = 0; mi < 4; ++mi)
#pragma unroll
                for (int ni = 0; ni < 2; ++ni)
                    acc[mi][ni] = __builtin_amdgcn_mfma_i32_16x16x64_i8(
                        af[mi], bfr[ni], acc[mi][ni], 0, 0, 0);
        }
        __syncthreads();
    }

    // --- Epilogue ---
    // C/D layout 16x16: col = lane&15 (c), row = q*4 + reg [m89/m91;
    // dtype-independent m121-m128]
    float sq_col[2];
    int lab_col[2];
#pragma unroll
    for (int ni = 0; ni < 2; ++ni) {
        const int gj = col0 + wc + ni * 16 + c;
        sq_col[ni] = sq[gj];
        lab_col[ni] = labels[gj];
    }
    int lab_row[4][4];
    float dist[4][2][4];
#pragma unroll
    for (int mi = 0; mi < 4; ++mi) {
#pragma unroll
        for (int r = 0; r < 4; ++r) {
            const int gi = row0 + mi * 16 + q * 4 + r;
            const float sqi = sq[gi];
            lab_row[mi][r] = labels[gi];
#pragma unroll
            for (int ni = 0; ni < 2; ++ni) {
                float d2 = sqi + sq_col[ni] - C2 * (float)acc[mi][ni][r];
                dist[mi][ni][r] = sqrtf(fmaxf(d2, 0.0f));
            }
        }
    }

    // Row-side: rows gi vs this wave's 32 columns.
#pragma unroll
    for (int mi = 0; mi < 4; ++mi) {
#pragma unroll
        for (int r = 0; r < 4; ++r) {
            const int gi = row0 + mi * 16 + q * 4 + r;
            const int li = lab_row[mi][r];
            float apm = 0.0f;
            float anm = __builtin_inff();
#pragma unroll
            for (int ni = 0; ni < 2; ++ni) {
                const int gj = col0 + wc + ni * 16 + c;
                const float d = dist[mi][ni][r];
                if (li == lab_col[ni]) {
                    if (gi != gj) apm = fmaxf(apm, d);  // exclude diagonal
                } else {
                    anm = fminf(anm, d);
                }
            }
#pragma unroll
            for (int off = 1; off < 16; off <<= 1) {
                apm = fmaxf(apm, __shfl_xor(apm, off, 16));
                anm = fminf(anm, __shfl_xor(anm, off, 16));
            }
            if (c == 0) {
                atomicMax(&ap[gi], __float_as_uint(apm));
                atomicMin(&an[gi], __float_as_uint(anm));
            }
        }
    }

    // Column-side (transposed): S(gi,gj) also serves row gj (dupes
    // idempotent; diagonal guarded).
#pragma unroll
    for (int ni = 0; ni < 2; ++ni) {
        const int gj = col0 + wc + ni * 16 + c;
        const int lj = lab_col[ni];
        float apm = 0.0f;
        float anm = __builtin_inff();
#pragma unroll
        for (int mi = 0; mi < 4; ++mi) {
#pragma unroll
            for (int r = 0; r < 4; ++r) {
                const int gi = row0 + mi * 16 + q * 4 + r;
                const float d = dist[mi][ni][r];
                if (lj == lab_row[mi][r]) {
                    if (gi != gj) apm = fmaxf(apm, d);  // exclude diagonal
                } else {
                    anm = fminf(anm, d);
                }
            }
        }
        apm = fmaxf(apm, __shfl_xor(apm, 16, 64));
        anm = fminf(anm, __shfl_xor(anm, 16, 64));
        apm = fmaxf(apm, __shfl_xor(apm, 32, 64));
        anm = fminf(anm, __shfl_xor(anm, 32, 64));
        if (q == 0) {
            atomicMax(&ap[gj], __float_as_uint(apm));
            atomicMin(&an[gj], __float_as_uint(anm));
        }
    }

    // --- Fused finalize: last block to finish reduces the loss ---
    __syncthreads();  // drains this block's atomics before counter release
    int* flag = (int*)As;
    if (t == 0) {
        int old = __hip_atomic_fetch_add(counter, 1, __ATOMIC_ACQ_REL,
                                         __HIP_MEMORY_SCOPE_AGENT);
        flag[0] = (old == NTILES - 1) ? 1 : 0;
    }
    __syncthreads();
    if (flag[0]) {
        float sum = 0.0f;
        int cnt = 0;
        for (int i = t; i < NN; i += 256) {
            const float a = __uint_as_float(__hip_atomic_load(
                &ap[i], __ATOMIC_RELAXED, __HIP_MEMORY_SCOPE_AGENT));
            const float b = __uint_as_float(__hip_atomic_load(
                &an[i], __ATOMIC_RELAXED, __HIP_MEMORY_SCOPE_AGENT));
            if ((a > 0.0f) && (b < __builtin_inff())) {
                sum += fmaxf(a - b + MARGIN_F, 0.0f);
                cnt += 1;
            }
        }
        for (int off = 32; off > 0; off >>= 1) {
            sum += __shfl_down(sum, off, 64);
            cnt += __shfl_down(cnt, off, 64);
        }
        float* ssum = (float*)Bs;
        int* scnt = (int*)Bs + 8;
        if (lane == 0) { ssum[wave] = sum; scnt[wave] = cnt; }
        __syncthreads();
        if (t == 0) {
            float s = 0.0f; int n = 0;
#pragma unroll
            for (int w = 0; w < 4; ++w) { s += ssum[w]; n += scnt[w]; }
            out[0] = (n > 0) ? s / (float)n : 0.0f;
        }
    }
}

extern "C" void kernel_launch(void* const* d_in, const int* in_sizes, int n_in,
                              void* d_out, int out_size, void* d_ws, size_t ws_size,
                              hipStream_t stream) {
    const float* x = (const float*)d_in[0];
    const int* labels = (const int*)d_in[1];
    float* out = (float*)d_out;

    char* ws = (char*)d_ws;
    unsigned char* xq = (unsigned char*)ws;                         // 4096*2048 B
    float* sq = (float*)(ws + (size_t)NN * DD);
    unsigned int* ap = (unsigned int*)(ws + (size_t)NN * DD + (size_t)NN * 4);
    unsigned int* an = (unsigned int*)(ws + (size_t)NN * DD + (size_t)NN * 8);
    int* counter = (int*)(ws + (size_t)NN * DD + (size_t)NN * 12);

    prep_kernel<<<NN / 4, 256, 0, stream>>>(x, xq, sq, ap, an, counter);
    gemm_reduce_kernel<<<NTILES, 256, 0, stream>>>(xq, sq, labels, ap, an, counter, out);
}